// Round 3
// baseline (166.856 us; speedup 1.0000x reference)
//
#include <hip/hip_runtime.h>

#define S_    2048
#define N_    16
#define OBS_  8
#define PRED_ 12
#define B_    (S_*N_)
#define SCN_  2     // scenes (waves) per block

typedef __attribute__((ext_vector_type(8))) short short8;
typedef __attribute__((ext_vector_type(4))) float floatx4;
typedef __attribute__((ext_vector_type(4))) unsigned uintx4;
typedef unsigned short ushort_t;

__device__ __forceinline__ float sigmf(float x) { return __builtin_amdgcn_rcpf(1.0f + __expf(-x)); }
__device__ __forceinline__ float tanhx(float x) { return fmaf(-2.0f, __builtin_amdgcn_rcpf(1.0f + __expf(2.0f*x)), 1.0f); }
// f32 -> bf16 round-half-up: bits+0x8000, truncate. <=0.5 ulp like RNE (ties differ only).
__device__ __forceinline__ unsigned bfhi(float f) {
  return __builtin_bit_cast(unsigned, f) + 0x8000u;
}
__device__ __forceinline__ unsigned pack2bf(float lo, float hi) {
  return __builtin_amdgcn_perm(bfhi(hi), bfhi(lo), 0x07060302);  // [hi.b3,hi.b2,lo.b3,lo.b2]
}
__device__ __forceinline__ ushort_t f2bf1(float f) { return (ushort_t)(bfhi(f) >> 16); }

// R16: LDS-pipe relief. R15 post-mortem: occupancy is capped by PROBLEM SIZE
// (2048 scenes = 2048 waves = 8 waves/CU); the shared per-CU LDS unit (~90 DS
// ops/wave/step x 8 waves ~= 7k cy/CU/step) is the serialization point, not
// barriers (0) and not VALU (~1.9k/wave/step across 4 SIMDs). This round moves
// LDS traffic to VALU+VGPRs (free up to 256 VGPR at 8 waves/CU):
//  - re tensor: recomputed IN the consuming lane per pool tile (bit-identical
//    fma nesting + pack pairing to the old LDS path) -> phase 3, re_s, its 8
//    b128 writes and 16 b128 reads all deleted.
//  - pool weights prW/prb (24 VGPR), out weights oW col + ob (17 VGPR): regs.
//  - pos: split posx_s/posy_s; per step 8 uniform-broadcast b128 reads into
//    regs + 2 lane reads; phase-5 update reuses the reg copy (no LDS RMW read).
//  - h pool-fragment hoisted out of the 16-tile loop (1 read, not 16).
// Barriers: ZERO (nothing cross-wave; weights read from global per wave).
// Numerics byte-identical to R15 (absmax 0.03125 expected unchanged).
// Tripwire: VGPR > 256 (drops to 4 waves/CU) or FETCH/WRITE balloon (spill).
extern "C" __global__ __launch_bounds__(128, 2) void traj_ar_kernel(
    const float* __restrict__ traj_rel, const float* __restrict__ obs_pos,
    const int*  __restrict__ nei,       const float* __restrict__ noise,
    const float* __restrict__ eeW, const float* __restrict__ eeb,
    const float* __restrict__ eWi, const float* __restrict__ eWh, const float* __restrict__ eb,
    const float* __restrict__ diW, const float* __restrict__ dib,
    const float* __restrict__ dWi, const float* __restrict__ dWh, const float* __restrict__ db,
    const float* __restrict__ prW, const float* __restrict__ prb,
    const float* __restrict__ mW,  const float* __restrict__ mb,
    const float* __restrict__ oW,  const float* __restrict__ ob,
    float* __restrict__ out)
{
  // per-scene (wave-private) state only — nothing cross-wave remains
  __shared__ __align__(16) float h_s[SCN_][256];       // f32 h, phase-5 input
  __shared__ __align__(16) float ctx_s[SCN_][256];     // f32 ctx, phase-5 input
  __shared__ __align__(16) ushort_t e_w[SCN_][384];    // bf16 e, stride 24/agent
  __shared__ __align__(16) ushort_t h_w[SCN_][384];    // bf16 h
  __shared__ __align__(16) ushort_t ctx_bf[SCN_][384]; // bf16 ctx, phase-1 B input
  __shared__ __align__(16) float posx_s[SCN_][16];
  __shared__ __align__(16) float posy_s[SCN_][16];
  __shared__ __align__(16) ushort_t prev_bf[SCN_][32];
  __shared__            unsigned sm_s[SCN_][16];

  const int tid = threadIdx.x;
  const int w  = tid >> 6;              // wave index == scene-within-block
  const int l  = tid & 63;
  const int lq = l >> 4;                // quad within wave
  const int lc = l & 15;                // col within wave (agent / unit-col)
  const int u0 = lq*4;                  // this lane's unit base
  const int s  = blockIdx.x*SCN_ + w;   // this wave's scene

  // ---- per-wave scene init (no cross-wave staging, no barrier) ----
  {
    // own wave's h0 = 0 and ctx0 = 0 (FULL 192 uints each — R13 lesson)
    unsigned* hz = (unsigned*)h_w[w];
    unsigned* cz = (unsigned*)ctx_bf[w];
    hz[l] = 0; hz[64+l] = 0; hz[128+l] = 0;
    cz[l] = 0; cz[64+l] = 0; cz[128+l] = 0;
  }
  if (l < 32) {
    const int a = l >> 1, c = l & 1;
    float pv = traj_rel[((OBS_-1)*B_ + s*N_ + a)*2 + c];
    prev_bf[w][a*2+c] = f2bf1(pv);                          // out init = traj_rel[OBS-1]
    float po = obs_pos[((OBS_-1)*B_ + s*N_ + a)*2 + c];
    if (c == 0) posx_s[w][a] = po; else posy_s[w][a] = po;
  }
  // time-invariant neighbor mask -> per-agent bitmask (wave-private)
  {
    const int a = l >> 2, nb = (l & 3)*4;
    const int4 nv = *(const int4*)&nei[(s*N_ + a)*N_ + nb];
    unsigned bits = 0;
    bits |= (nv.x > 0) ? (1u << (nb+0)) : 0u;
    bits |= (nv.y > 0) ? (1u << (nb+1)) : 0u;
    bits |= (nv.z > 0) ? (1u << (nb+2)) : 0u;
    bits |= (nv.w > 0) ? (1u << (nb+3)) : 0u;
    bits |= __shfl_xor(bits, 1, 64);
    bits |= __shfl_xor(bits, 2, 64);
    if ((l & 3) == 0) sm_s[w][a] = bits;
  }

  // pool-MLP B-fragment (32x16 bf16 weights)
  short8 bfrag;
  {
    uintx4 bw;
    #pragma unroll
    for (int p = 0; p < 4; ++p)
      bw[p] = pack2bf(mW[(8*lq + 2*p)*16 + lc], mW[(8*lq + 2*p + 1)*16 + lc]);
    bfrag = __builtin_bit_cast(short8, bw);
  }
  const float bm = mb[lc];

  // pool-rel weights for this lane's A-fragment unit octet u=(lq&1)*8..+7
  // (only lq<2 lanes consume; (lq&1) keeps addresses valid for all lanes)
  float pWx[8], pWy[8], pB[8];
  {
    const int wu0 = (lq & 1) * 8;
    #pragma unroll
    for (int j = 0; j < 8; ++j) {
      pWx[j] = prW[wu0 + j];
      pWy[j] = prW[16 + wu0 + j];
      pB[j]  = prb[wu0 + j];
    }
  }

  // out-layer column for this lane's output lq, + bias
  float oWc[16];
  #pragma unroll
  for (int m = 0; m < 16; ++m) oWc[m] = oW[m*4 + lq];
  const float obia = ob[lq];

  // encoder embed weights for this lane's 4 units
  float ew0[4], ew1[4], ebv[4];
  #pragma unroll
  for (int r = 0; r < 4; ++r) {
    ew0[r] = eeW[u0+r]; ew1[r] = eeW[16+u0+r]; ebv[r] = eeb[u0+r];
  }

  const int row0 = (lq & 1) * 8;

  // gate A-fragment for gate g (A[row=lc][k] = W[k][g*16+lc]) + bias C by D-row unit
  #define LOAD_GATE_FRAG(A, C, Wi_, Wh_, bias_, g) {                                      \
    const float* gsrc_ = (lq & 2) ? (Wh_) : (Wi_);                                        \
    uintx4 aw_;                                                                           \
    aw_[0] = pack2bf(gsrc_[(row0+0)*64 + (g)*16 + lc], gsrc_[(row0+1)*64 + (g)*16 + lc]); \
    aw_[1] = pack2bf(gsrc_[(row0+2)*64 + (g)*16 + lc], gsrc_[(row0+3)*64 + (g)*16 + lc]); \
    aw_[2] = pack2bf(gsrc_[(row0+4)*64 + (g)*16 + lc], gsrc_[(row0+5)*64 + (g)*16 + lc]); \
    aw_[3] = pack2bf(gsrc_[(row0+6)*64 + (g)*16 + lc], gsrc_[(row0+7)*64 + (g)*16 + lc]); \
    (A) = __builtin_bit_cast(short8, aw_);                                                \
    (C)[0] = (bias_)[(g)*16 + u0 + 0]; (C)[1] = (bias_)[(g)*16 + u0 + 1];                 \
    (C)[2] = (bias_)[(g)*16 + u0 + 2]; (C)[3] = (bias_)[(g)*16 + u0 + 3];                 \
  }

  // encoder gate A-frags, all 4 gates on this wave
  short8 eA0, eA1, eA2, eA3; floatx4 eC0, eC1, eC2, eC3;
  LOAD_GATE_FRAG(eA0, eC0, eWi, eWh, eb, 0);
  LOAD_GATE_FRAG(eA1, eC1, eWi, eWh, eb, 1);
  LOAD_GATE_FRAG(eA2, eC2, eWi, eWh, eb, 2);
  LOAD_GATE_FRAG(eA3, eC3, eWi, eWh, eb, 3);

  #define LSTM_EW(r, hv) {                                                            \
    float ig = sigmf(dI[r]), fg = sigmf(dF[r]), gv = tanhx(dG[r]), og = sigmf(dO[r]); \
    c4[r] = fg*c4[r] + ig*gv;                                                         \
    hv = og * tanhx(c4[r]);                                                           \
  }

  // ---- encoder: 8 LSTM steps, zero barriers (all hand-offs same-wave LDS) ----
  floatx4 c4 = {0.0f, 0.0f, 0.0f, 0.0f};
  const float2* xr2 = (const float2*)traj_rel;
  for (int t = 0; t < OBS_; ++t) {
    float2 x = xr2[t*B_ + s*N_ + lc];
    float e0 = fmaxf(fmaf(x.y, ew1[0], fmaf(x.x, ew0[0], ebv[0])), 0.0f);
    float e1 = fmaxf(fmaf(x.y, ew1[1], fmaf(x.x, ew0[1], ebv[1])), 0.0f);
    float e2 = fmaxf(fmaf(x.y, ew1[2], fmaf(x.x, ew0[2], ebv[2])), 0.0f);
    float e3 = fmaxf(fmaf(x.y, ew1[3], fmaf(x.x, ew0[3], ebv[3])), 0.0f);
    uint2 ep; ep.x = pack2bf(e0, e1); ep.y = pack2bf(e2, e3);
    *(uint2*)&e_w[w][lc*24 + u0] = ep;               // same-wave cross-lane hand-off
    const ushort_t* bp = (lq < 2) ? &e_w[w][lc*24 + (lq&1)*8] : &h_w[w][lc*24 + (lq&1)*8];
    short8 bfr = *(const short8*)bp;
    floatx4 dI = __builtin_amdgcn_mfma_f32_16x16x32_bf16(eA0, bfr, eC0, 0, 0, 0);
    floatx4 dF = __builtin_amdgcn_mfma_f32_16x16x32_bf16(eA1, bfr, eC1, 0, 0, 0);
    floatx4 dG = __builtin_amdgcn_mfma_f32_16x16x32_bf16(eA2, bfr, eC2, 0, 0, 0);
    floatx4 dO = __builtin_amdgcn_mfma_f32_16x16x32_bf16(eA3, bfr, eC3, 0, 0, 0);
    float h40, h41, h42, h43;
    LSTM_EW(0, h40); LSTM_EW(1, h41); LSTM_EW(2, h42); LSTM_EW(3, h43);
    uint2 hp2; hp2.x = pack2bf(h40, h41); hp2.y = pack2bf(h42, h43);
    *(uint2*)&h_w[w][lc*24 + u0] = hp2;
  }

  // decoder gate A-frags (separate live range from encoder's)
  short8 dA0, dA1, dA2, dA3; floatx4 dC0, dC1, dC2, dC3;
  LOAD_GATE_FRAG(dA0, dC0, dWi, dWh, db, 0);
  LOAD_GATE_FRAG(dA1, dC1, dWi, dWh, db, 1);
  LOAD_GATE_FRAG(dA2, dC2, dWi, dWh, db, 2);
  LOAD_GATE_FRAG(dA3, dC3, dWi, dWh, db, 3);

  // dec-in A-fragment: kk 0..15 = ctx rows, 16,17 = prev rows, 18..31 zero-pad
  short8 diA; floatx4 diC;
  {
    uintx4 aw; aw[0]=0; aw[1]=0; aw[2]=0; aw[3]=0;
    if (lq < 2) {
      const int r0 = lq*8;
      #pragma unroll
      for (int p = 0; p < 4; ++p)
        aw[p] = pack2bf(diW[(r0+2*p)*16 + lc], diW[(r0+2*p+1)*16 + lc]);
    } else if (lq == 2) {
      aw[0] = pack2bf(diW[16*16 + lc], diW[17*16 + lc]);
    }
    diA = __builtin_bit_cast(short8, aw);
    #pragma unroll
    for (int r = 0; r < 4; ++r) diC[r] = dib[u0 + r];
  }

  // pool C-operands, all 16 target agents, mask baked (time-invariant).
  // 64 VGPR; every access below is constant-indexed via full unroll (rule #20).
  floatx4 cm[16];
  #pragma unroll
  for (int tt = 0; tt < 16; ++tt) {
    const unsigned mi = sm_s[w][tt];
    #pragma unroll
    for (int r = 0; r < 4; ++r)
      cm[tt][r] = ((mi >> (u0 + r)) & 1u) ? bm : -1e9f;
  }

  // ---- decoder: 12 autoregressive steps, ZERO barriers ----
  c4 = (floatx4){0.0f, 0.0f, 0.0f, 0.0f};
  const int MU_OFF = PRED_*B_*2;
  const int SD_OFF = 2*PRED_*B_*2;
  for (int t = 0; t < PRED_; ++t) {
    // early noise load: consumed in phase 5
    const float nz = noise[(t*B_ + s*N_ + lc)*2 + (lq&1)];
    // phase 0: pos snapshot into regs (8 uniform-broadcast b128 + 2 lane reads;
    // sees prev step's phase-5 writes — same-wave program order)
    const floatx4 PX0 = *(const floatx4*)&posx_s[w][0];
    const floatx4 PX1 = *(const floatx4*)&posx_s[w][4];
    const floatx4 PX2 = *(const floatx4*)&posx_s[w][8];
    const floatx4 PX3 = *(const floatx4*)&posx_s[w][12];
    const floatx4 PY0 = *(const floatx4*)&posy_s[w][0];
    const floatx4 PY1 = *(const floatx4*)&posy_s[w][4];
    const floatx4 PY2 = *(const floatx4*)&posy_s[w][8];
    const floatx4 PY3 = *(const floatx4*)&posy_s[w][12];
    const float mx = posx_s[w][lc];
    const float my = posy_s[w][lc];
    // phase 1: e = relu([ctx|prev] @ dec_in_W + b) via MFMA
    {
      short8 cv = *(const short8*)&ctx_bf[w][lc*24 + (lq&1)*8];
      uintx4 pz; pz[0] = *(const unsigned*)&prev_bf[w][lc*2]; pz[1]=0; pz[2]=0; pz[3]=0;
      short8 pv = __builtin_bit_cast(short8, pz);
      short8 zz = {0,0,0,0,0,0,0,0};
      short8 bf1 = (lq < 2) ? cv : ((lq == 2) ? pv : zz);
      floatx4 d = __builtin_amdgcn_mfma_f32_16x16x32_bf16(diA, bf1, diC, 0, 0, 0);
      uint2 ep;
      ep.x = pack2bf(fmaxf(d[0],0.0f), fmaxf(d[1],0.0f));
      ep.y = pack2bf(fmaxf(d[2],0.0f), fmaxf(d[3],0.0f));
      *(uint2*)&e_w[w][lc*24 + u0] = ep;
    }
    // phase 2: 4 gate MFMAs + elementwise; h -> bf16 (pool/gates) + f32 (phase 5)
    {
      const ushort_t* bp = (lq < 2) ? &e_w[w][lc*24 + (lq&1)*8] : &h_w[w][lc*24 + (lq&1)*8];
      short8 bfr = *(const short8*)bp;
      floatx4 dI = __builtin_amdgcn_mfma_f32_16x16x32_bf16(dA0, bfr, dC0, 0, 0, 0);
      floatx4 dF = __builtin_amdgcn_mfma_f32_16x16x32_bf16(dA1, bfr, dC1, 0, 0, 0);
      floatx4 dG = __builtin_amdgcn_mfma_f32_16x16x32_bf16(dA2, bfr, dC2, 0, 0, 0);
      floatx4 dO = __builtin_amdgcn_mfma_f32_16x16x32_bf16(dA3, bfr, dC3, 0, 0, 0);
      float h40, h41, h42, h43;
      LSTM_EW(0, h40); LSTM_EW(1, h41); LSTM_EW(2, h42); LSTM_EW(3, h43);
      uint2 hp2; hp2.x = pack2bf(h40, h41); hp2.y = pack2bf(h42, h43);
      *(uint2*)&h_w[w][lc*24 + u0] = hp2;
      floatx4 hv4; hv4[0]=h40; hv4[1]=h41; hv4[2]=h42; hv4[3]=h43;
      *(floatx4*)&h_s[w][lc*16 + u0] = hv4;
    }
    // pool h A-fragment: hoisted, ONE read for all 16 tiles (after h_w write)
    const short8 hfrag = *(const short8*)&h_w[w][lc*24 + (lq&1)*8];
    // phase 4: masked max-pool; re recomputed IN-LANE per tile (no LDS transit).
    // A[j=lc][k=(lq&1)*8+jj] = relu((pos[tt]-pos[lc]) @ prW + prb)[unit k] —
    // bit-identical fma nesting + pack pairing to the old phase-3 LDS path.
    {
      #pragma unroll
      for (int tt = 0; tt < 16; ++tt) {
        const floatx4 PXq = (tt<4)?PX0:(tt<8)?PX1:(tt<12)?PX2:PX3;
        const floatx4 PYq = (tt<4)?PY0:(tt<8)?PY1:(tt<12)?PY2:PY3;
        const float rx = PXq[tt&3] - mx;
        const float ry = PYq[tt&3] - my;
        float rr[8];
        #pragma unroll
        for (int j = 0; j < 8; ++j)
          rr[j] = fmaxf(fmaf(ry, pWy[j], fmaf(rx, pWx[j], pB[j])), 0.0f);
        uintx4 aw;
        aw[0] = pack2bf(rr[0], rr[1]);
        aw[1] = pack2bf(rr[2], rr[3]);
        aw[2] = pack2bf(rr[4], rr[5]);
        aw[3] = pack2bf(rr[6], rr[7]);
        const short8 refrag = __builtin_bit_cast(short8, aw);
        short8 a = (lq < 2) ? refrag : hfrag;
        floatx4 d = __builtin_amdgcn_mfma_f32_16x16x32_bf16(a, bfrag, cm[tt], 0, 0, 0);
        float pm = fmaxf(fmaxf(d[0], d[1]), fmaxf(d[2], d[3]));
        pm = fmaxf(pm, __shfl_xor(pm, 16, 64));
        pm = fmaxf(pm, __shfl_xor(pm, 32, 64));
        if (lq == (tt & 3)) {
          float cvv = fmaxf(pm, 0.0f);
          ctx_s[w][tt*16 + lc] = cvv;
          ctx_bf[w][tt*24 + lc] = f2bf1(cvv);
        }
      }
    }
    // phase 5: o4 = (h+ctx)@out_W + b with out-weights in regs; outputs +
    // pos/prev advance (pos written from the reg copy mx/my — no LDS RMW read)
    {
      float acc = obia;
      const floatx4* hp4 = (const floatx4*)&h_s[w][lc*16];
      const floatx4* cx4 = (const floatx4*)&ctx_s[w][lc*16];
      #pragma unroll
      for (int mm = 0; mm < 4; ++mm) {
        floatx4 hv = hp4[mm];
        floatx4 cv = cx4[mm];
        #pragma unroll
        for (int r = 0; r < 4; ++r)
          acc = fmaf(hv[r]+cv[r], oWc[mm*4+r], acc);
      }
      float sc = __shfl_down(acc, 32, 64);   // lq<2 grabs o4[lq+2]
      if (lq < 2) {
        float mu = acc;
        float scale = fminf(fmaxf(sc, -9.0f), 4.0f);
        float sd = __expf(scale);
        float pr = fmaf(sd, nz, mu);
        int o = (t*B_ + s*N_ + lc)*2 + lq;
        out[o]          = pr;
        out[MU_OFF + o] = mu;
        out[SD_OFF + o] = sd;
        if (lq == 0) posx_s[w][lc] = mx + pr;
        else         posy_s[w][lc] = my + pr;
        prev_bf[w][lc*2+lq] = f2bf1(pr);
      }
    }
  }
  #undef LSTM_EW
  #undef LOAD_GATE_FRAG
}

extern "C" void kernel_launch(void* const* d_in, const int* in_sizes, int n_in,
                              void* d_out, int out_size, void* d_ws, size_t ws_size,
                              hipStream_t stream) {
  (void)in_sizes; (void)n_in; (void)d_ws; (void)ws_size; (void)out_size;
  traj_ar_kernel<<<dim3(S_/SCN_), dim3(128), 0, stream>>>(
      (const float*)d_in[0],  (const float*)d_in[1],  (const int*)d_in[2],   (const float*)d_in[3],
      (const float*)d_in[4],  (const float*)d_in[5],  (const float*)d_in[6], (const float*)d_in[7],
      (const float*)d_in[8],  (const float*)d_in[9],  (const float*)d_in[10],(const float*)d_in[11],
      (const float*)d_in[12], (const float*)d_in[13], (const float*)d_in[14],(const float*)d_in[15],
      (const float*)d_in[16], (const float*)d_in[17], (const float*)d_in[18],(const float*)d_in[19],
      (float*)d_out);
}

// Round 5
// 160.028 us; speedup vs baseline: 1.0427x; 1.0427x over previous
//
#include <hip/hip_runtime.h>

#define S_    2048
#define N_    16
#define OBS_  8
#define PRED_ 12
#define B_    (S_*N_)
#define SCN_  2     // scenes (waves) per block

typedef __attribute__((ext_vector_type(8))) short short8;
typedef __attribute__((ext_vector_type(4))) float floatx4;
typedef __attribute__((ext_vector_type(4))) unsigned uintx4;
typedef unsigned short ushort_t;

__device__ __forceinline__ float sigmf(float x) { return __builtin_amdgcn_rcpf(1.0f + __expf(-x)); }
__device__ __forceinline__ float tanhx(float x) { return fmaf(-2.0f, __builtin_amdgcn_rcpf(1.0f + __expf(2.0f*x)), 1.0f); }
// f32 -> bf16 round-half-up: bits+0x8000, truncate. <=0.5 ulp like RNE (ties differ only).
__device__ __forceinline__ unsigned bfhi(float f) {
  return __builtin_bit_cast(unsigned, f) + 0x8000u;
}
__device__ __forceinline__ unsigned pack2bf(float lo, float hi) {
  return __builtin_amdgcn_perm(bfhi(hi), bfhi(lo), 0x07060302);  // [hi.b3,hi.b2,lo.b3,lo.b2]
}
__device__ __forceinline__ ushort_t f2bf1(float f) { return (ushort_t)(bfhi(f) >> 16); }
__device__ __forceinline__ float rlanef(float v, int lane) {
  return __builtin_bit_cast(float, __builtin_amdgcn_readlane(__builtin_bit_cast(int, v), lane));
}

// R18 = R17 with the cross-half routing FIXED. R17 post-mortem: the
// v_permlane32_swap_b32 asm assumed D.lo<->S.hi but HW does D.hi<->S.lo
// (permlane16 analogy) -> uninitialized s0.lo fed the t1-MFMA and a0.lo was
// clobbered -> NaN. Fix: route re(t1) from lanes 32-63 into lanes 0-31 with
// __shfl_xor(x,32,64) — the SAME primitive already proven on `pm` below
// (defined semantics, full-wave bpermute crossbar). 4 bpermutes/pair x 8
// pairs = 32 DS ops/step, ~1.2x permlane cost (m255) — negligible.
// Changes vs R16 (all BIT-EXACT; absmax must be 0.03125 or it's a routing bug):
//  1. pair-tile re: lanes<32 compute re(t0), lanes>=32 re(t1) (was: computed
//     twice, half discarded); shfl_xor(32) routes t1's fragment down. ~-150
//     VALU/step net of the shuffles.
//  2. pos de-LDS: POSX/POSY per-lane regs; per-step 32 v_readlane -> uniform
//     snapshot; update POSX += shfl(pr,lc). Same f32 ops.
//  3. prev de-LDS: prevu reg = pack2bf(shfl(pr,lc), shfl(pr,16+lc)).
// Remaining LDS: e_w/h_w (MFMA B-operand transposes), ctx_s/ctx_bf (unit->agent
// transpose), h_s (phase-5 row gather), sm_s. Zero barriers (wave-per-scene).
// Tripwires: absmax != 0.03125 -> bug; VGPR > 256 or FETCH/WRITE balloon -> spill.
extern "C" __global__ __launch_bounds__(128, 2) void traj_ar_kernel(
    const float* __restrict__ traj_rel, const float* __restrict__ obs_pos,
    const int*  __restrict__ nei,       const float* __restrict__ noise,
    const float* __restrict__ eeW, const float* __restrict__ eeb,
    const float* __restrict__ eWi, const float* __restrict__ eWh, const float* __restrict__ eb,
    const float* __restrict__ diW, const float* __restrict__ dib,
    const float* __restrict__ dWi, const float* __restrict__ dWh, const float* __restrict__ db,
    const float* __restrict__ prW, const float* __restrict__ prb,
    const float* __restrict__ mW,  const float* __restrict__ mb,
    const float* __restrict__ oW,  const float* __restrict__ ob,
    float* __restrict__ out)
{
  // per-scene (wave-private) state only — nothing cross-wave
  __shared__ __align__(16) float h_s[SCN_][256];       // f32 h, phase-5 input
  __shared__ __align__(16) float ctx_s[SCN_][256];     // f32 ctx, phase-5 input
  __shared__ __align__(16) ushort_t e_w[SCN_][384];    // bf16 e, stride 24/agent
  __shared__ __align__(16) ushort_t h_w[SCN_][384];    // bf16 h
  __shared__ __align__(16) ushort_t ctx_bf[SCN_][384]; // bf16 ctx, phase-1 B input
  __shared__            unsigned sm_s[SCN_][16];

  const int tid = threadIdx.x;
  const int w  = tid >> 6;              // wave index == scene-within-block
  const int l  = tid & 63;
  const int lq = l >> 4;                // quad within wave
  const int lc = l & 15;                // col within wave (agent / unit-col)
  const int u0 = lq*4;                  // this lane's unit base
  const int s  = blockIdx.x*SCN_ + w;   // this wave's scene
  const bool hi_half = (lq >= 2);       // lanes 32..63

  // ---- per-wave scene init (no barriers anywhere) ----
  {
    // own wave's h0 = 0 and ctx0 = 0 (FULL 192 uints each — R13 lesson)
    unsigned* hz = (unsigned*)h_w[w];
    unsigned* cz = (unsigned*)ctx_bf[w];
    hz[l] = 0; hz[64+l] = 0; hz[128+l] = 0;
    cz[l] = 0; cz[64+l] = 0; cz[128+l] = 0;
  }
  // pos + prev live in REGISTERS (R17 changes 2/3, unchanged)
  float POSX = obs_pos[((OBS_-1)*B_ + s*N_ + lc)*2 + 0];
  float POSY = obs_pos[((OBS_-1)*B_ + s*N_ + lc)*2 + 1];
  unsigned prevu;
  {
    float pvx = traj_rel[((OBS_-1)*B_ + s*N_ + lc)*2 + 0];
    float pvy = traj_rel[((OBS_-1)*B_ + s*N_ + lc)*2 + 1];
    prevu = pack2bf(pvx, pvy);          // [y_bf | x_bf], same bits as old LDS path
  }
  // time-invariant neighbor mask -> per-agent bitmask (wave-private)
  {
    const int a = l >> 2, nb = (l & 3)*4;
    const int4 nv = *(const int4*)&nei[(s*N_ + a)*N_ + nb];
    unsigned bits = 0;
    bits |= (nv.x > 0) ? (1u << (nb+0)) : 0u;
    bits |= (nv.y > 0) ? (1u << (nb+1)) : 0u;
    bits |= (nv.z > 0) ? (1u << (nb+2)) : 0u;
    bits |= (nv.w > 0) ? (1u << (nb+3)) : 0u;
    bits |= __shfl_xor(bits, 1, 64);
    bits |= __shfl_xor(bits, 2, 64);
    if ((l & 3) == 0) sm_s[w][a] = bits;
  }

  // pool-MLP B-fragment (32x16 bf16 weights)
  short8 bfrag;
  {
    uintx4 bw;
    #pragma unroll
    for (int p = 0; p < 4; ++p)
      bw[p] = pack2bf(mW[(8*lq + 2*p)*16 + lc], mW[(8*lq + 2*p + 1)*16 + lc]);
    bfrag = __builtin_bit_cast(short8, bw);
  }
  const float bm = mb[lc];

  // pool-rel weights for this lane's unit octet (lq&1)*8..+7
  float pWx[8], pWy[8], pB[8];
  {
    const int wu0 = (lq & 1) * 8;
    #pragma unroll
    for (int j = 0; j < 8; ++j) {
      pWx[j] = prW[wu0 + j];
      pWy[j] = prW[16 + wu0 + j];
      pB[j]  = prb[wu0 + j];
    }
  }

  // out-layer column for this lane's output lq, + bias
  float oWc[16];
  #pragma unroll
  for (int m = 0; m < 16; ++m) oWc[m] = oW[m*4 + lq];
  const float obia = ob[lq];

  // encoder embed weights for this lane's 4 units
  float ew0[4], ew1[4], ebv[4];
  #pragma unroll
  for (int r = 0; r < 4; ++r) {
    ew0[r] = eeW[u0+r]; ew1[r] = eeW[16+u0+r]; ebv[r] = eeb[u0+r];
  }

  const int row0 = (lq & 1) * 8;

  // gate A-fragment for gate g (A[row=lc][k] = W[k][g*16+lc]) + bias C by D-row unit
  #define LOAD_GATE_FRAG(A, C, Wi_, Wh_, bias_, g) {                                      \
    const float* gsrc_ = (lq & 2) ? (Wh_) : (Wi_);                                        \
    uintx4 aw_;                                                                           \
    aw_[0] = pack2bf(gsrc_[(row0+0)*64 + (g)*16 + lc], gsrc_[(row0+1)*64 + (g)*16 + lc]); \
    aw_[1] = pack2bf(gsrc_[(row0+2)*64 + (g)*16 + lc], gsrc_[(row0+3)*64 + (g)*16 + lc]); \
    aw_[2] = pack2bf(gsrc_[(row0+4)*64 + (g)*16 + lc], gsrc_[(row0+5)*64 + (g)*16 + lc]); \
    aw_[3] = pack2bf(gsrc_[(row0+6)*64 + (g)*16 + lc], gsrc_[(row0+7)*64 + (g)*16 + lc]); \
    (A) = __builtin_bit_cast(short8, aw_);                                                \
    (C)[0] = (bias_)[(g)*16 + u0 + 0]; (C)[1] = (bias_)[(g)*16 + u0 + 1];                 \
    (C)[2] = (bias_)[(g)*16 + u0 + 2]; (C)[3] = (bias_)[(g)*16 + u0 + 3];                 \
  }

  // encoder gate A-frags, all 4 gates on this wave
  short8 eA0, eA1, eA2, eA3; floatx4 eC0, eC1, eC2, eC3;
  LOAD_GATE_FRAG(eA0, eC0, eWi, eWh, eb, 0);
  LOAD_GATE_FRAG(eA1, eC1, eWi, eWh, eb, 1);
  LOAD_GATE_FRAG(eA2, eC2, eWi, eWh, eb, 2);
  LOAD_GATE_FRAG(eA3, eC3, eWi, eWh, eb, 3);

  #define LSTM_EW(r, hv) {                                                            \
    float ig = sigmf(dI[r]), fg = sigmf(dF[r]), gv = tanhx(dG[r]), og = sigmf(dO[r]); \
    c4[r] = fg*c4[r] + ig*gv;                                                         \
    hv = og * tanhx(c4[r]);                                                           \
  }

  // ---- encoder: 8 LSTM steps, zero barriers (same-wave LDS hand-offs) ----
  floatx4 c4 = {0.0f, 0.0f, 0.0f, 0.0f};
  const float2* xr2 = (const float2*)traj_rel;
  for (int t = 0; t < OBS_; ++t) {
    float2 x = xr2[t*B_ + s*N_ + lc];
    float e0 = fmaxf(fmaf(x.y, ew1[0], fmaf(x.x, ew0[0], ebv[0])), 0.0f);
    float e1 = fmaxf(fmaf(x.y, ew1[1], fmaf(x.x, ew0[1], ebv[1])), 0.0f);
    float e2 = fmaxf(fmaf(x.y, ew1[2], fmaf(x.x, ew0[2], ebv[2])), 0.0f);
    float e3 = fmaxf(fmaf(x.y, ew1[3], fmaf(x.x, ew0[3], ebv[3])), 0.0f);
    uint2 ep; ep.x = pack2bf(e0, e1); ep.y = pack2bf(e2, e3);
    *(uint2*)&e_w[w][lc*24 + u0] = ep;
    const ushort_t* bp = (lq < 2) ? &e_w[w][lc*24 + (lq&1)*8] : &h_w[w][lc*24 + (lq&1)*8];
    short8 bfr = *(const short8*)bp;
    floatx4 dI = __builtin_amdgcn_mfma_f32_16x16x32_bf16(eA0, bfr, eC0, 0, 0, 0);
    floatx4 dF = __builtin_amdgcn_mfma_f32_16x16x32_bf16(eA1, bfr, eC1, 0, 0, 0);
    floatx4 dG = __builtin_amdgcn_mfma_f32_16x16x32_bf16(eA2, bfr, eC2, 0, 0, 0);
    floatx4 dO = __builtin_amdgcn_mfma_f32_16x16x32_bf16(eA3, bfr, eC3, 0, 0, 0);
    float h40, h41, h42, h43;
    LSTM_EW(0, h40); LSTM_EW(1, h41); LSTM_EW(2, h42); LSTM_EW(3, h43);
    uint2 hp2; hp2.x = pack2bf(h40, h41); hp2.y = pack2bf(h42, h43);
    *(uint2*)&h_w[w][lc*24 + u0] = hp2;
  }

  // decoder gate A-frags (separate live range from encoder's)
  short8 dA0, dA1, dA2, dA3; floatx4 dC0, dC1, dC2, dC3;
  LOAD_GATE_FRAG(dA0, dC0, dWi, dWh, db, 0);
  LOAD_GATE_FRAG(dA1, dC1, dWi, dWh, db, 1);
  LOAD_GATE_FRAG(dA2, dC2, dWi, dWh, db, 2);
  LOAD_GATE_FRAG(dA3, dC3, dWi, dWh, db, 3);

  // dec-in A-fragment: kk 0..15 = ctx rows, 16,17 = prev rows, 18..31 zero-pad
  short8 diA; floatx4 diC;
  {
    uintx4 aw; aw[0]=0; aw[1]=0; aw[2]=0; aw[3]=0;
    if (lq < 2) {
      const int r0 = lq*8;
      #pragma unroll
      for (int p = 0; p < 4; ++p)
        aw[p] = pack2bf(diW[(r0+2*p)*16 + lc], diW[(r0+2*p+1)*16 + lc]);
    } else if (lq == 2) {
      aw[0] = pack2bf(diW[16*16 + lc], diW[17*16 + lc]);
    }
    diA = __builtin_bit_cast(short8, aw);
    #pragma unroll
    for (int r = 0; r < 4; ++r) diC[r] = dib[u0 + r];
  }

  // pool C-operands, all 16 target agents, mask baked (time-invariant).
  floatx4 cm[16];
  #pragma unroll
  for (int tt = 0; tt < 16; ++tt) {
    const unsigned mi = sm_s[w][tt];
    #pragma unroll
    for (int r = 0; r < 4; ++r)
      cm[tt][r] = ((mi >> (u0 + r)) & 1u) ? bm : -1e9f;
  }

  // ---- decoder: 12 autoregressive steps, ZERO barriers ----
  c4 = (floatx4){0.0f, 0.0f, 0.0f, 0.0f};
  const int MU_OFF = PRED_*B_*2;
  const int SD_OFF = 2*PRED_*B_*2;
  for (int t = 0; t < PRED_; ++t) {
    // early noise load: consumed in phase 5
    const float nz = noise[(t*B_ + s*N_ + lc)*2 + (lq&1)];
    // phase 0: all-agent pos snapshot -> uniform regs (32 v_readlane, no LDS RT)
    float PXs[16], PYs[16];
    #pragma unroll
    for (int a2 = 0; a2 < 16; ++a2) {
      PXs[a2] = rlanef(POSX, a2);
      PYs[a2] = rlanef(POSY, a2);
    }
    // phase 1: e = relu([ctx|prev] @ dec_in_W + b) via MFMA (prev from reg)
    {
      short8 cv = *(const short8*)&ctx_bf[w][lc*24 + (lq&1)*8];
      uintx4 pz; pz[0] = prevu; pz[1]=0; pz[2]=0; pz[3]=0;
      short8 pv = __builtin_bit_cast(short8, pz);
      short8 zz = {0,0,0,0,0,0,0,0};
      short8 bf1 = (lq < 2) ? cv : ((lq == 2) ? pv : zz);
      floatx4 d = __builtin_amdgcn_mfma_f32_16x16x32_bf16(diA, bf1, diC, 0, 0, 0);
      uint2 ep;
      ep.x = pack2bf(fmaxf(d[0],0.0f), fmaxf(d[1],0.0f));
      ep.y = pack2bf(fmaxf(d[2],0.0f), fmaxf(d[3],0.0f));
      *(uint2*)&e_w[w][lc*24 + u0] = ep;
    }
    // phase 2: 4 gate MFMAs + elementwise; h -> bf16 (pool/gates) + f32 (phase 5)
    {
      const ushort_t* bp = (lq < 2) ? &e_w[w][lc*24 + (lq&1)*8] : &h_w[w][lc*24 + (lq&1)*8];
      short8 bfr = *(const short8*)bp;
      floatx4 dI = __builtin_amdgcn_mfma_f32_16x16x32_bf16(dA0, bfr, dC0, 0, 0, 0);
      floatx4 dF = __builtin_amdgcn_mfma_f32_16x16x32_bf16(dA1, bfr, dC1, 0, 0, 0);
      floatx4 dG = __builtin_amdgcn_mfma_f32_16x16x32_bf16(dA2, bfr, dC2, 0, 0, 0);
      floatx4 dO = __builtin_amdgcn_mfma_f32_16x16x32_bf16(dA3, bfr, dC3, 0, 0, 0);
      float h40, h41, h42, h43;
      LSTM_EW(0, h40); LSTM_EW(1, h41); LSTM_EW(2, h42); LSTM_EW(3, h43);
      uint2 hp2; hp2.x = pack2bf(h40, h41); hp2.y = pack2bf(h42, h43);
      *(uint2*)&h_w[w][lc*24 + u0] = hp2;
      floatx4 hv4; hv4[0]=h40; hv4[1]=h41; hv4[2]=h42; hv4[3]=h43;
      *(floatx4*)&h_s[w][lc*16 + u0] = hv4;
    }
    // pool h A-fragment: hoisted, ONE read for all 16 tiles (after h_w write)
    const short8 hfrag = *(const short8*)&h_w[w][lc*24 + (lq&1)*8];
    // phase 4: masked max-pool, 8 tile-PAIRS. Lower half-wave computes re for
    // tile t0, upper half for t1; __shfl_xor(.,32) (defined full-wave crossbar,
    // same primitive as the pm reduction) routes t1's fragment into lanes<32.
    // fma nesting + pack pairing bit-identical to R16.
    {
      #pragma unroll
      for (int p = 0; p < 8; ++p) {
        const int t0 = 2*p, t1 = 2*p + 1;
        float rx0 = PXs[t0] - POSX, ry0 = PYs[t0] - POSY;
        float rx1 = PXs[t1] - POSX, ry1 = PYs[t1] - POSY;
        float rx = hi_half ? rx1 : rx0;
        float ry = hi_half ? ry1 : ry0;
        float rr[8];
        #pragma unroll
        for (int j = 0; j < 8; ++j)
          rr[j] = fmaxf(fmaf(ry, pWy[j], fmaf(rx, pWx[j], pB[j])), 0.0f);
        unsigned a0 = pack2bf(rr[0], rr[1]);
        unsigned a1 = pack2bf(rr[2], rr[3]);
        unsigned a2 = pack2bf(rr[4], rr[5]);
        unsigned a3 = pack2bf(rr[6], rr[7]);
        // route re(t1) (lives in lanes 32-63) into lanes 0-31
        unsigned s0 = __shfl_xor(a0, 32, 64);
        unsigned s1 = __shfl_xor(a1, 32, 64);
        unsigned s2 = __shfl_xor(a2, 32, 64);
        unsigned s3 = __shfl_xor(a3, 32, 64);
        uintx4 f0; f0[0]=a0; f0[1]=a1; f0[2]=a2; f0[3]=a3;
        uintx4 f1; f1[0]=s0; f1[1]=s1; f1[2]=s2; f1[3]=s3;
        const short8 reA = __builtin_bit_cast(short8, f0);
        const short8 reB = __builtin_bit_cast(short8, f1);
        // tile t0
        {
          short8 a = hi_half ? hfrag : reA;
          floatx4 d = __builtin_amdgcn_mfma_f32_16x16x32_bf16(a, bfrag, cm[t0], 0, 0, 0);
          float pm = fmaxf(fmaxf(d[0], d[1]), fmaxf(d[2], d[3]));
          pm = fmaxf(pm, __shfl_xor(pm, 16, 64));
          pm = fmaxf(pm, __shfl_xor(pm, 32, 64));
          if (lq == (t0 & 3)) {
            float cvv = fmaxf(pm, 0.0f);
            ctx_s[w][t0*16 + lc] = cvv;
            ctx_bf[w][t0*24 + lc] = f2bf1(cvv);
          }
        }
        // tile t1
        {
          short8 a = hi_half ? hfrag : reB;
          floatx4 d = __builtin_amdgcn_mfma_f32_16x16x32_bf16(a, bfrag, cm[t1], 0, 0, 0);
          float pm = fmaxf(fmaxf(d[0], d[1]), fmaxf(d[2], d[3]));
          pm = fmaxf(pm, __shfl_xor(pm, 16, 64));
          pm = fmaxf(pm, __shfl_xor(pm, 32, 64));
          if (lq == (t1 & 3)) {
            float cvv = fmaxf(pm, 0.0f);
            ctx_s[w][t1*16 + lc] = cvv;
            ctx_bf[w][t1*24 + lc] = f2bf1(cvv);
          }
        }
      }
    }
    // phase 5: o4 = (h+ctx)@out_W + b; pr computed in ALL lanes (stores guarded);
    // pos/prev advance via shuffle broadcasts into regs (no LDS RT)
    {
      float acc = obia;
      const floatx4* hp4 = (const floatx4*)&h_s[w][lc*16];
      const floatx4* cx4 = (const floatx4*)&ctx_s[w][lc*16];
      #pragma unroll
      for (int mm = 0; mm < 4; ++mm) {
        floatx4 hv = hp4[mm];
        floatx4 cv = cx4[mm];
        #pragma unroll
        for (int r = 0; r < 4; ++r)
          acc = fmaf(hv[r]+cv[r], oWc[mm*4+r], acc);
      }
      float sc = __shfl_down(acc, 32, 64);   // lq<2 grabs o4[lq+2]
      float mu = acc;
      float scale = fminf(fmaxf(sc, -9.0f), 4.0f);
      float sd = __expf(scale);
      float pr = fmaf(sd, nz, mu);
      if (lq < 2) {
        int o = (t*B_ + s*N_ + lc)*2 + lq;
        out[o]          = pr;
        out[MU_OFF + o] = mu;
        out[SD_OFF + o] = sd;
      }
      float prx = __shfl(pr, lc, 64);        // agent lc's x-delta (lane lc)
      float pry = __shfl(pr, 16 + lc, 64);   // agent lc's y-delta (lane 16+lc)
      POSX += prx;
      POSY += pry;
      prevu = pack2bf(prx, pry);             // same bits as old prev_bf path
    }
  }
  #undef LSTM_EW
  #undef LOAD_GATE_FRAG
}

extern "C" void kernel_launch(void* const* d_in, const int* in_sizes, int n_in,
                              void* d_out, int out_size, void* d_ws, size_t ws_size,
                              hipStream_t stream) {
  (void)in_sizes; (void)n_in; (void)d_ws; (void)ws_size; (void)out_size;
  traj_ar_kernel<<<dim3(S_/SCN_), dim3(128), 0, stream>>>(
      (const float*)d_in[0],  (const float*)d_in[1],  (const int*)d_in[2],   (const float*)d_in[3],
      (const float*)d_in[4],  (const float*)d_in[5],  (const float*)d_in[6], (const float*)d_in[7],
      (const float*)d_in[8],  (const float*)d_in[9],  (const float*)d_in[10],(const float*)d_in[11],
      (const float*)d_in[12], (const float*)d_in[13], (const float*)d_in[14],(const float*)d_in[15],
      (const float*)d_in[16], (const float*)d_in[17], (const float*)d_in[18],(const float*)d_in[19],
      (float*)d_out);
}